// Round 4
// baseline (1165.403 us; speedup 1.0000x reference)
//
#include <hip/hip_runtime.h>
#include <hip/hip_bf16.h>
#include <math.h>

#define N_PTS 100000
#define P_PROP 256
#define R_FEAT 256
#define NCLS 21          // C + 1
#define NCHG 4           // channel groups of 64
#define CHG 64

// ---------------- Kernel A: scatter-accumulate ------------------------------
// grid = NCHG * nchunk blocks, 256 threads (4 waves).
// Block (g, chunk): LDS acc[256 proposals][64 channels] (64 KB).
// Each wave walks its points serially (wave-uniform point index):
//   - 4 ballot iters test the point vs 64 register-cached boxes per lane
//     -> 256-bit hitmask (wave-uniform u64 x4)
//   - lane = channel: v = feats[pt][g*64+lane] (one coalesced 256B load)
//   - bit-scan loop: one ds_add_f32 per hit proposal.
// feats is read ONCE per channel-group (102 MB total) instead of once per
// (proposal,point) hit (794 MB) -- the reuse lives in LDS now.
__global__ __launch_bounds__(256) void accum_kernel(
    const float* __restrict__ proposals,   // (P,6)
    const float* __restrict__ xyz,         // (N,3)
    const float* __restrict__ feats,       // (N,R)
    float* __restrict__ partials,          // (NCHG, nchunk, P, CHG)
    float* __restrict__ pcounts,           // (nchunk, P)
    int nchunk, int chunk_len)
{
    const int bid = blockIdx.x;
    const int g = bid & 3;
    const int chunk = bid >> 2;
    const int t = threadIdx.x;
    const int lane = t & 63;
    const int wave = __builtin_amdgcn_readfirstlane(t >> 6);

    __shared__ float acc[P_PROP * CHG];    // 64 KB
    __shared__ float cntred[4][P_PROP];    // 4 KB

    // zero accumulators
    float4* acc4 = (float4*)acc;
    for (int j = t; j < (P_PROP * CHG) / 4; j += 256)
        acc4[j] = make_float4(0.f, 0.f, 0.f, 0.f);

    // cache bounds for proposals lane, 64+lane, 128+lane, 192+lane in VGPRs
    float lox[4], hix[4], loy[4], hiy[4], loz[4], hiz[4];
#pragma unroll
    for (int k = 0; k < 4; ++k) {
        const int p = (k << 6) | lane;
        const float cx = proposals[p * 6 + 0];
        const float cy = proposals[p * 6 + 1];
        const float cz = proposals[p * 6 + 2];
        const float hx = proposals[p * 6 + 3] * 0.5f;
        const float hy = proposals[p * 6 + 4] * 0.5f;
        const float hz = proposals[p * 6 + 5] * 0.5f;
        lox[k] = cx - hx; hix[k] = cx + hx;
        loy[k] = cy - hy; hiy[k] = cy + hy;
        loz[k] = cz - hz; hiz[k] = cz + hz;
    }
    __syncthreads();

    const int start = chunk * chunk_len;
    const int end = min(start + chunk_len, N_PTS);

    int cnt0 = 0, cnt1 = 0, cnt2 = 0, cnt3 = 0;   // per-lane box counts (g==0)

    for (int i = start + wave; i < end; i += 4) {
        // issue the feature load early; mask VALU hides part of its latency
        const float v = feats[(size_t)i * R_FEAT + (g << 6) + lane];
        const float px = xyz[3 * i + 0];
        const float py = xyz[3 * i + 1];
        const float pz = xyz[3 * i + 2];

        unsigned long long hm[4];
        {
            bool in0 = (px >= lox[0]) & (px <= hix[0]) & (py >= loy[0]) & (py <= hiy[0]) & (pz >= loz[0]) & (pz <= hiz[0]);
            bool in1 = (px >= lox[1]) & (px <= hix[1]) & (py >= loy[1]) & (py <= hiy[1]) & (pz >= loz[1]) & (pz <= hiz[1]);
            bool in2 = (px >= lox[2]) & (px <= hix[2]) & (py >= loy[2]) & (py <= hiy[2]) & (pz >= loz[2]) & (pz <= hiz[2]);
            bool in3 = (px >= lox[3]) & (px <= hix[3]) & (py >= loy[3]) & (py <= hiy[3]) & (pz >= loz[3]) & (pz <= hiz[3]);
            hm[0] = __ballot(in0); hm[1] = __ballot(in1);
            hm[2] = __ballot(in2); hm[3] = __ballot(in3);
            cnt0 += in0; cnt1 += in1; cnt2 += in2; cnt3 += in3;
        }

#pragma unroll
        for (int k = 0; k < 4; ++k) {
            unsigned long long w = hm[k];
            while (w) {
                const int b = __builtin_ctzll(w);
                w &= (w - 1);
                const int prop = (k << 6) | b;
                atomicAdd(&acc[(prop << 6) | lane], v);   // ds_add_f32, 2 lanes/bank: free
            }
        }
    }

    __syncthreads();

    // write partials: linear j -> (p = j>>6, ch = j&63), coalesced
    const size_t base = ((size_t)(g * nchunk + chunk)) * (size_t)(P_PROP * CHG);
    for (int j = t; j < P_PROP * CHG; j += 256)
        partials[base + j] = acc[j];

    if (g == 0) {
        cntred[wave][(0 << 6) | lane] = (float)cnt0;
        cntred[wave][(1 << 6) | lane] = (float)cnt1;
        cntred[wave][(2 << 6) | lane] = (float)cnt2;
        cntred[wave][(3 << 6) | lane] = (float)cnt3;
        __syncthreads();
        pcounts[chunk * P_PROP + t] =
            cntred[0][t] + cntred[1][t] + cntred[2][t] + cntred[3][t];
    }
}

// ---------------- Kernel B: reduce partials + both logit heads -------------
// grid = P blocks, 256 threads. Thread t = (g = t>>6, ch = t&63) -> channel t.
__global__ __launch_bounds__(256) void head_kernel(
    const float* __restrict__ partials,  // (NCHG, nchunk, P, CHG)
    const float* __restrict__ pcounts,   // (nchunk, P)
    const float* __restrict__ Wc,        // (R,21)
    const float* __restrict__ bc,        // (21)
    const float* __restrict__ Wo,        // (R,21)
    const float* __restrict__ bo,        // (21)
    float* __restrict__ cls_logits,      // (P,21)
    float* __restrict__ obj_logits,      // (P,21)
    int nchunk)
{
    const int p = blockIdx.x;
    const int t = threadIdx.x;
    const int g = t >> 6;
    const int ch = t & 63;

    __shared__ float roi[R_FEAT];
    __shared__ float red[256];
    __shared__ float part[4][64];

    float sum = 0.0f;
    for (int c = 0; c < nchunk; ++c)
        sum += partials[((size_t)(g * nchunk + c) * P_PROP + p) * CHG + ch];

    float csum = 0.0f;
    for (int c = t; c < nchunk; c += 256)
        csum += pcounts[c * P_PROP + p];
    red[t] = csum;
    __syncthreads();
    for (int s = 128; s > 0; s >>= 1) {
        if (t < s) red[t] += red[t + s];
        __syncthreads();
    }
    const float cntv = fmaxf(red[0], 1.0f);

    roi[t] = sum / cntv;    // channel index == t
    __syncthreads();

    const int c2 = t & 63;
    const int qk = t >> 6;
    float accv = 0.0f;
    if (c2 < 2 * NCLS) {
        const float* __restrict__ W = (c2 < NCLS) ? Wc : Wo;
        const int cc = (c2 < NCLS) ? c2 : c2 - NCLS;
        const int r0 = qk * 64;
#pragma unroll
        for (int r = 0; r < 64; ++r)
            accv = fmaf(roi[r0 + r], W[(r0 + r) * NCLS + cc], accv);
    }
    part[qk][c2] = accv;
    __syncthreads();

    if (t < 2 * NCLS) {
        const float v = part[0][t] + part[1][t] + part[2][t] + part[3][t];
        if (t < NCLS) cls_logits[p * NCLS + t] = v + bc[t];
        else          obj_logits[p * NCLS + (t - NCLS)] = v + bo[t - NCLS];
    }
}

// ---------------- Kernel C: softmaxes + elementwise product ----------------
// single block, 256 threads; thread t = proposal t for the row softmax;
// (g = t>>5, cc = t&31) for the 8-way-parallel column reductions.
__global__ __launch_bounds__(256) void softmax_mul_kernel(
    const float* __restrict__ cls_logits,  // (P,21)
    const float* __restrict__ obj_logits,  // (P,21)
    float* __restrict__ out)               // (P,21)
{
    const int t = threadIdx.x;
    const int cc = t & 31;
    const int g = t >> 5;

    __shared__ float objl[P_PROP][NCLS];
    __shared__ float red[8][32];
    __shared__ float colmax[32];
    __shared__ float colsum[32];

    float cl[NCLS], ob[NCLS];
#pragma unroll
    for (int c = 0; c < NCLS; ++c) {
        cl[c] = cls_logits[t * NCLS + c];
        ob[c] = obj_logits[t * NCLS + c];
        objl[t][c] = ob[c];
    }
    __syncthreads();

    float m = -INFINITY;
    if (cc < NCLS) {
        const int p0 = g * 32;
        for (int p = p0; p < p0 + 32; ++p) m = fmaxf(m, objl[p][cc]);
    }
    red[g][cc] = m;
    __syncthreads();
    if (t < NCLS) {
        float mm = red[0][t];
#pragma unroll
        for (int gg = 1; gg < 8; ++gg) mm = fmaxf(mm, red[gg][t]);
        colmax[t] = mm;
    }
    __syncthreads();

    float sc = 0.0f;
    if (cc < NCLS) {
        const float mm = colmax[cc];
        const int p0 = g * 32;
        for (int p = p0; p < p0 + 32; ++p) sc += expf(objl[p][cc] - mm);
    }
    red[g][cc] = sc;
    __syncthreads();
    if (t < NCLS) {
        float ss = red[0][t];
#pragma unroll
        for (int gg = 1; gg < 8; ++gg) ss += red[gg][t];
        colsum[t] = ss;
    }

    float rm = cl[0];
#pragma unroll
    for (int c = 1; c < NCLS; ++c) rm = fmaxf(rm, cl[c]);
    float e[NCLS];
    float rs = 0.0f;
#pragma unroll
    for (int c = 0; c < NCLS; ++c) { e[c] = expf(cl[c] - rm); rs += e[c]; }
    const float inv = 1.0f / rs;

    __syncthreads();

#pragma unroll
    for (int c = 0; c < NCLS; ++c) {
        const float cp = e[c] * inv;
        const float op = expf(ob[c] - colmax[c]) / colsum[c];
        out[t * NCLS + c] = cp * op;
    }
}

// ---------------- launch ----------------------------------------------------
extern "C" void kernel_launch(void* const* d_in, const int* in_sizes, int n_in,
                              void* d_out, int out_size, void* d_ws, size_t ws_size,
                              hipStream_t stream) {
    const float* proposals = (const float*)d_in[0];  // (256,6)
    const float* xyz       = (const float*)d_in[1];  // (100000,3)
    const float* feats     = (const float*)d_in[2];  // (100000,256)
    const float* Wc        = (const float*)d_in[3];  // (256,21)
    const float* bc        = (const float*)d_in[4];  // (21)
    const float* Wo        = (const float*)d_in[5];  // (256,21)
    const float* bo        = (const float*)d_in[6];  // (21)
    float* out = (float*)d_out;                      // (256,21)

    // nchunk=128 -> 512 blocks (2/CU), partials = 32 MiB. Fall back to 64
    // chunks (16 MiB) if the workspace is small.
    const size_t need128 = (size_t)NCHG * 128 * P_PROP * CHG * 4
                         + (size_t)128 * P_PROP * 4 + 2 * 21504 + 4096;
    const int nchunk = (ws_size >= need128) ? 128 : 64;
    const int chunk_len = (N_PTS + nchunk - 1) / nchunk;

    char* ws = (char*)d_ws;
    size_t off = 0;
    float* partials = (float*)(ws + off);
    off += (size_t)NCHG * nchunk * P_PROP * CHG * 4;
    float* pcounts = (float*)(ws + off);
    off += (size_t)nchunk * P_PROP * 4;
    float* clsl = (float*)(ws + off);
    off += (size_t)P_PROP * NCLS * 4;
    float* objl = (float*)(ws + off);

    accum_kernel<<<NCHG * nchunk, 256, 0, stream>>>(proposals, xyz, feats,
                                                    partials, pcounts,
                                                    nchunk, chunk_len);
    head_kernel<<<P_PROP, 256, 0, stream>>>(partials, pcounts, Wc, bc, Wo, bo,
                                            clsl, objl, nchunk);
    softmax_mul_kernel<<<1, 256, 0, stream>>>(clsl, objl, out);
}

// Round 5
// 285.190 us; speedup vs baseline: 4.0864x; 4.0864x over previous
//
#include <hip/hip_runtime.h>
#include <hip/hip_bf16.h>
#include <math.h>

#define N_PTS 100000
#define P_PROP 256
#define R_FEAT 256
#define NCLS 21              // C + 1
#define NWORDS 1563          // ceil(N_PTS/64)
#define MROW 1568            // padded u64 words per proposal row
#define WPS 49               // mask words per gather segment
#define NSEG 32              // ceil(1563/49)
#define LIST_MAX 3136        // WPS*64
#define MASK_BLOCKS 392      // 392*4 waves >= 1563 groups
#define ZERO_PER_BLK 168     // floats zeroed per mask block (392*168*4 = 263424 B)

// ws layout (bytes):
//   0        sums     256*256*4 = 262144
//   262144   counts   256*4
//   263168   colsum   21*4  (zero region padded to 263424)
//   263424   cls_p    256*21*4 = 21504
//   284928   eobj     21504
//   306432   mask_t   256*1568*8 = 3211264
#define WS_SUMS    0
#define WS_COUNTS  262144
#define WS_COLSUM  263168
#define WS_ZEROEND 263424
#define WS_CLSP    263424
#define WS_EOBJ    284928
#define WS_MASK    306432

// ---------------- Kernel 1: per-point hitmasks (transposed) + ws zeroing ----
// grid = 392 blocks x 256 threads. Wave w handles point-group gi = bid*4+w
// (64 points, lane = point). Loops the 256 proposals (bounds in LDS): ballot
// -> wave-uniform u64 -> mask_t[p][gi]. Each block also zeros its slice of
// the sums/counts/colsum region (stream order guarantees completion before
// the gather kernel's atomics).
__global__ __launch_bounds__(256) void mask_kernel(
    const float* __restrict__ proposals,   // (P,6)
    const float* __restrict__ xyz,         // (N,3)
    float* __restrict__ ws_zero,           // zero region base (floats)
    unsigned long long* __restrict__ mask_t) // (P, MROW)
{
    const int bid = blockIdx.x;
    const int t = threadIdx.x;
    const int wave = t >> 6;
    const int lane = t & 63;

    // zero the accumulator region
    {
        float* z = ws_zero + (size_t)bid * ZERO_PER_BLK;
        for (int j = t; j < ZERO_PER_BLK; j += 256) z[j] = 0.0f;
    }

    __shared__ float lox[P_PROP], hix[P_PROP];
    __shared__ float loy[P_PROP], hiy[P_PROP];
    __shared__ float loz[P_PROP], hiz[P_PROP];
    {
        const float cx = proposals[t * 6 + 0];
        const float cy = proposals[t * 6 + 1];
        const float cz = proposals[t * 6 + 2];
        const float hx = proposals[t * 6 + 3] * 0.5f;
        const float hy = proposals[t * 6 + 4] * 0.5f;
        const float hz = proposals[t * 6 + 5] * 0.5f;
        lox[t] = cx - hx; hix[t] = cx + hx;
        loy[t] = cy - hy; hiy[t] = cy + hy;
        loz[t] = cz - hz; hiz[t] = cz + hz;
    }
    __syncthreads();

    const int gi = bid * 4 + wave;
    if (gi >= NWORDS) return;

    const int i = gi * 64 + lane;
    float px = 3.0e9f, py = 3.0e9f, pz = 3.0e9f;   // outside any box
    if (i < N_PTS) {
        px = xyz[3 * i + 0];
        py = xyz[3 * i + 1];
        pz = xyz[3 * i + 2];
    }

    for (int p = 0; p < P_PROP; ++p) {
        const bool in = (px >= lox[p]) & (px <= hix[p]) &
                        (py >= loy[p]) & (py <= hiy[p]) &
                        (pz >= loz[p]) & (pz <= hiz[p]);
        const unsigned long long w = __ballot(in);
        if (lane == 0) mask_t[(size_t)p * MROW + gi] = w;
    }
}

// ---------------- Kernel 2: gather + global-atomic accumulate --------------
// grid = 8192 blocks (s = bid>>8, p = bid&255), 256 threads (4 waves).
// Compaction from ~49 mask words (no xyz reads). Gather: wave-strided rows,
// float4/lane, 8 rows in flight (R3-proven). Accumulate into sums[P][R] via
// fire-and-forget global atomics; one count atomic per block.
__global__ __launch_bounds__(256) void gather_kernel(
    const float* __restrict__ feats,                 // (N,R)
    const unsigned long long* __restrict__ mask_t,   // (P, MROW)
    float* __restrict__ sums,                        // (P,R)
    float* __restrict__ counts)                      // (P)
{
    const int bid = blockIdx.x;
    const int s = bid >> 8;
    const int p = bid & (P_PROP - 1);
    const int t = threadIdx.x;
    const int wave = t >> 6;
    const int lane = t & 63;

    __shared__ int list[LIST_MAX];
    __shared__ float red[4][R_FEAT];
    __shared__ int cnt;

    if (t == 0) cnt = 0;
    __syncthreads();

    const int g0 = s * WPS;
    const int g1 = min(g0 + WPS, NWORDS);
    const unsigned long long* mrow = mask_t + (size_t)p * MROW;

    for (int g = g0 + wave; g < g1; g += 4) {
        const unsigned long long w = mrow[g];          // wave-uniform 8B load
        const int nb = __popcll(w);
        if (nb == 0) continue;
        const int prefix = __popcll(w & ((1ull << lane) - 1ull));
        const bool in = (w >> lane) & 1ull;
        int base = 0;
        if (lane == 0) base = atomicAdd(&cnt, nb);
        base = __shfl(base, 0, 64);
        if (in) list[base + prefix] = g * 64 + lane;
    }
    __syncthreads();

    const int m = cnt;

    // gather: wave-strided rows, float4 per lane, 8 rows in flight
    float4 acc = make_float4(0.f, 0.f, 0.f, 0.f);
    int j = wave;
    for (; j + 28 < m; j += 32) {
        int r[8];
#pragma unroll
        for (int u = 0; u < 8; ++u) r[u] = list[j + 4 * u];
        float4 f[8];
#pragma unroll
        for (int u = 0; u < 8; ++u)
            f[u] = *(const float4*)(feats + (size_t)r[u] * R_FEAT + lane * 4);
#pragma unroll
        for (int u = 0; u < 8; ++u) {
            acc.x += f[u].x; acc.y += f[u].y; acc.z += f[u].z; acc.w += f[u].w;
        }
    }
    for (; j < m; j += 4) {
        const int r = list[j];
        const float4 f = *(const float4*)(feats + (size_t)r * R_FEAT + lane * 4);
        acc.x += f.x; acc.y += f.y; acc.z += f.z; acc.w += f.w;
    }

    // cross-wave reduction: wave w's lane L holds channels 4L..4L+3
    *(float4*)(&red[wave][lane * 4]) = acc;
    __syncthreads();

    const float sum = red[0][t] + red[1][t] + red[2][t] + red[3][t];
    atomicAdd(&sums[p * R_FEAT + t], sum);
    if (t == 0 && m > 0) atomicAdd(&counts[p], (float)m);
}

// ---------------- Kernel 3: heads + cls softmax + exp(obj) -----------------
// grid = P blocks, 256 threads.
__global__ __launch_bounds__(256) void head_kernel(
    const float* __restrict__ sums,      // (P,R)
    const float* __restrict__ counts,    // (P)
    const float* __restrict__ Wc,        // (R,21)
    const float* __restrict__ bc,        // (21)
    const float* __restrict__ Wo,        // (R,21)
    const float* __restrict__ bo,        // (21)
    float* __restrict__ cls_p,           // (P,21)
    float* __restrict__ eobj,            // (P,21)
    float* __restrict__ colsum)          // (21)
{
    const int p = blockIdx.x;
    const int t = threadIdx.x;

    __shared__ float roi[R_FEAT];
    __shared__ float part[4][64];
    __shared__ float lg[48];
    __shared__ float cmax, csum;

    const float cntv = fmaxf(counts[p], 1.0f);
    roi[t] = sums[p * R_FEAT + t] / cntv;
    __syncthreads();

    const int c2 = t & 63;
    const int qk = t >> 6;
    float accv = 0.0f;
    if (c2 < 2 * NCLS) {
        const float* __restrict__ W = (c2 < NCLS) ? Wc : Wo;
        const int cc = (c2 < NCLS) ? c2 : c2 - NCLS;
        const int r0 = qk * 64;
#pragma unroll
        for (int r = 0; r < 64; ++r)
            accv = fmaf(roi[r0 + r], W[(r0 + r) * NCLS + cc], accv);
    }
    part[qk][c2] = accv;
    __syncthreads();

    if (t < 2 * NCLS) {
        const float v = part[0][t] + part[1][t] + part[2][t] + part[3][t];
        lg[t] = v + ((t < NCLS) ? bc[t] : bo[t - NCLS]);
    }
    __syncthreads();

    if (t == 0) {
        float m = lg[0];
        for (int c = 1; c < NCLS; ++c) m = fmaxf(m, lg[c]);
        float sacc = 0.0f;
        for (int c = 0; c < NCLS; ++c) sacc += expf(lg[c] - m);
        cmax = m; csum = sacc;
    }
    __syncthreads();

    if (t < NCLS) {
        cls_p[p * NCLS + t] = expf(lg[t] - cmax) / csum;
    } else if (t >= NCLS && t < 2 * NCLS) {
        const int c = t - NCLS;
        const float eo = expf(lg[t]);      // |logit| ~ 0.02: no max needed
        eobj[p * NCLS + c] = eo;
        atomicAdd(&colsum[c], eo);
    }
}

// ---------------- Kernel 4: final product ----------------------------------
__global__ __launch_bounds__(256) void final_kernel(
    const float* __restrict__ cls_p,   // (P,21)
    const float* __restrict__ eobj,    // (P,21)
    const float* __restrict__ colsum,  // (21)
    float* __restrict__ out)           // (P,21)
{
    const int t = threadIdx.x;
    for (int k = t; k < P_PROP * NCLS; k += 256) {
        const int p = k / NCLS;
        const int c = k - p * NCLS;
        out[k] = cls_p[k] * eobj[k] / colsum[c];
    }
}

// ---------------- launch ----------------------------------------------------
extern "C" void kernel_launch(void* const* d_in, const int* in_sizes, int n_in,
                              void* d_out, int out_size, void* d_ws, size_t ws_size,
                              hipStream_t stream) {
    const float* proposals = (const float*)d_in[0];  // (256,6)
    const float* xyz       = (const float*)d_in[1];  // (100000,3)
    const float* feats     = (const float*)d_in[2];  // (100000,256)
    const float* Wc        = (const float*)d_in[3];  // (256,21)
    const float* bc        = (const float*)d_in[4];  // (21)
    const float* Wo        = (const float*)d_in[5];  // (256,21)
    const float* bo        = (const float*)d_in[6];  // (21)
    float* out = (float*)d_out;                      // (256,21)

    char* ws = (char*)d_ws;
    float* sums    = (float*)(ws + WS_SUMS);
    float* counts  = (float*)(ws + WS_COUNTS);
    float* colsum  = (float*)(ws + WS_COLSUM);
    float* cls_p   = (float*)(ws + WS_CLSP);
    float* eobj    = (float*)(ws + WS_EOBJ);
    unsigned long long* mask_t = (unsigned long long*)(ws + WS_MASK);

    mask_kernel<<<MASK_BLOCKS, 256, 0, stream>>>(proposals, xyz,
                                                 (float*)(ws + WS_SUMS), mask_t);
    gather_kernel<<<P_PROP * NSEG, 256, 0, stream>>>(feats, mask_t, sums, counts);
    head_kernel<<<P_PROP, 256, 0, stream>>>(sums, counts, Wc, bc, Wo, bo,
                                            cls_p, eobj, colsum);
    final_kernel<<<1, 256, 0, stream>>>(cls_p, eobj, colsum, out);
}

// Round 6
// 256.659 us; speedup vs baseline: 4.5407x; 1.1112x over previous
//
#include <hip/hip_runtime.h>
#include <math.h>

#define N_PTS 100000
#define P_PROP 256
#define R_FEAT 256
#define NCLS 21              // C + 1
#define KB_TOT 12800         // point-bytes (covers 102400 padded points)
#define MB_BLOCKS 400        // mask blocks; block b covers points [b*256, b*256+256)
#define KC 800               // points per gemm k-chunk
#define KSTEPS 25            // KC / 32
#define NCHUNK 128           // NCHUNK * KC = 102400
#define KB_CHUNK 100         // KC / 8 mask bytes per chunk

// ws layout (bytes):
#define WS_SUMS    0         // 256*256*4 = 262144 (zeroed by mask kernel)
#define WS_COLSUM  262144    // 21*4, zero region padded to 262400
#define WS_PCNT    262400    // 400*256*4 = 409600
#define WS_CLSP    672000    // 21504
#define WS_EOBJ    693504    // 21504
#define WS_MASK    715008    // 12800*256 = 3276800  (ends 3991808)

typedef _Float16 half8 __attribute__((ext_vector_type(8)));
typedef float f32x4 __attribute__((ext_vector_type(4)));

// ---------------- Kernel 1: transposed byte-mask + partial counts ----------
// grid = 400 blocks x 256 threads (4 waves). Wave w owns points
// [b*256 + w*64, +64) (lane = point). p-loop over 256 proposals (bounds in
// LDS): ballot -> u64 -> LDS wd[p][w]. Then: thread t = proposal t sums
// popcounts -> pcnt[b][t]; transpose-write 32 mask rows (256 B each) to
// maskT[kb][p]. Also zeros the sums+colsum region (stream-ordered before
// the GEMM's atomics).
__global__ __launch_bounds__(256) void mask_kernel(
    const float* __restrict__ proposals,   // (P,6)
    const float* __restrict__ xyz,         // (N,3)
    unsigned char* __restrict__ maskT,     // (KB_TOT, 256)
    float* __restrict__ pcnt,              // (MB_BLOCKS, 256)
    float* __restrict__ ws_zero)           // 65600 floats to zero
{
    const int b = blockIdx.x;
    const int t = threadIdx.x;
    const int wave = t >> 6;
    const int lane = t & 63;

    // zero slice of sums+colsum (400 blocks x 164 floats = 65600)
    {
        float* z = ws_zero + b * 164;
        for (int j = t; j < 164; j += 256) z[j] = 0.0f;
    }

    __shared__ float lox[P_PROP], hix[P_PROP];
    __shared__ float loy[P_PROP], hiy[P_PROP];
    __shared__ float loz[P_PROP], hiz[P_PROP];
    __shared__ unsigned long long wd[P_PROP][4];   // [p][wave]

    {
        const float cx = proposals[t * 6 + 0];
        const float cy = proposals[t * 6 + 1];
        const float cz = proposals[t * 6 + 2];
        const float hx = proposals[t * 6 + 3] * 0.5f;
        const float hy = proposals[t * 6 + 4] * 0.5f;
        const float hz = proposals[t * 6 + 5] * 0.5f;
        lox[t] = cx - hx; hix[t] = cx + hx;
        loy[t] = cy - hy; hiy[t] = cy + hy;
        loz[t] = cz - hz; hiz[t] = cz + hz;
    }
    __syncthreads();

    const int i = b * 256 + wave * 64 + lane;     // global point index
    float px = 3.0e9f, py = 3.0e9f, pz = 3.0e9f;  // outside every box
    if (i < N_PTS) {
        px = xyz[3 * i + 0];
        py = xyz[3 * i + 1];
        pz = xyz[3 * i + 2];
    }

    for (int p = 0; p < P_PROP; ++p) {
        const bool in = (px >= lox[p]) & (px <= hix[p]) &
                        (py >= loy[p]) & (py <= hiy[p]) &
                        (pz >= loz[p]) & (pz <= hiz[p]);
        const unsigned long long w = __ballot(in);
        if (lane == 0) wd[p][wave] = w;
    }
    __syncthreads();

    // partial counts: thread t = proposal t (integers, exact in fp32)
    {
        const unsigned long long* q = wd[t];
        const int c = __popcll(q[0]) + __popcll(q[1]) +
                      __popcll(q[2]) + __popcll(q[3]);
        pcnt[b * 256 + t] = (float)c;
    }

    // transpose-write: rows kb = b*32 + r, byte (kb, p) = wd bytes at p*32+kb_local
    const int r = t >> 3;        // 0..31 local kb
    const int seg = t & 7;       // p-range [seg*32, +32)
    const unsigned char* wb = (const unsigned char*)wd;
    unsigned int outw[8];
#pragma unroll
    for (int d = 0; d < 8; ++d) {
        unsigned int v = 0;
#pragma unroll
        for (int u = 0; u < 4; ++u) {
            const int p = seg * 32 + d * 4 + u;
            v |= ((unsigned int)wb[p * 32 + r]) << (8 * u);
        }
        outw[d] = v;
    }
    unsigned int* dst = (unsigned int*)(maskT + ((size_t)(b * 32 + r)) * 256 + seg * 32);
#pragma unroll
    for (int d = 0; d < 8; ++d) dst[d] = outw[d];
}

// ---------------- Kernel 2: dense masked-sum GEMM via f16 MFMA -------------
// grid = 512 blocks = 128 k-chunks x 4 channel-tiles. Block: 256 threads
// (4 waves), tile M=256 proposals x N=64 channels x K=800 points.
// Wave w owns proposals [w*64, +64) (4 M-subtiles) x all 4 N-subtiles.
// Per 32-point k-step: stage feats as packed f16 [ch][k] in LDS; A-fragment
// = mask byte expanded to 8 f16 {0,1}; 16 MFMA (16x16x32 f16). fp32 acc.
// Epilogue: global fp32 atomicAdd into sums[P][R].
__global__ __launch_bounds__(256) void gemm_kernel(
    const float* __restrict__ feats,               // (N,R)
    const unsigned char* __restrict__ maskT,       // (KB_TOT, 256)
    float* __restrict__ sums)                      // (P,R)
{
    const int bid = blockIdx.x;
    const int nt4 = bid & 3;
    const int chunk = bid >> 2;
    const int ch0 = nt4 * 64;
    const int t = threadIdx.x;
    const int wave = t >> 6;
    const int lane = t & 63;
    const int quad = lane >> 4;
    const int m16 = lane & 15;

    __shared__ __align__(16) unsigned char mbuf[KB_CHUNK * 256];   // 25600 B
    __shared__ __align__(16) _Float16 Bbuf[64][40];                // 5120 B (k padded 32->40)

    // load this chunk's mask slice (contiguous 25600 B)
    {
        const int4* src = (const int4*)(maskT + (size_t)chunk * (KB_CHUNK * 256));
        int4* dstv = (int4*)mbuf;
        for (int j = t; j < (KB_CHUNK * 256) / 16; j += 256) dstv[j] = src[j];
    }

    f32x4 acc[4][4];
#pragma unroll
    for (int mt = 0; mt < 4; ++mt)
#pragma unroll
        for (int nt = 0; nt < 4; ++nt)
            acc[mt][nt] = (f32x4)0.0f;

    __syncthreads();

    const int kbase = chunk * KC;
    for (int step = 0; step < KSTEPS; ++step) {
        // ---- stage B: 32 rows x 64 ch fp32 -> packed f16 [ch][k] ----
        {
            const int ch = t & 63;
            const int g = t >> 6;
#pragma unroll
            for (int u = 0; u < 4; ++u) {
                const int kp = g + 4 * u;                 // 0..15 (pair index)
                int r0 = kbase + step * 32 + 2 * kp;
                int r1 = r0 + 1;
                r0 = min(r0, N_PTS - 1);                  // clamp; mask=0 there
                r1 = min(r1, N_PTS - 1);
                const float f0 = feats[(size_t)r0 * R_FEAT + ch0 + ch];
                const float f1 = feats[(size_t)r1 * R_FEAT + ch0 + ch];
                const _Float16 h0 = (_Float16)f0;
                const _Float16 h1 = (_Float16)f1;
                const unsigned int pk =
                    ((unsigned int)__builtin_bit_cast(unsigned short, h1) << 16) |
                    (unsigned int)__builtin_bit_cast(unsigned short, h0);
                *(unsigned int*)&Bbuf[ch][2 * kp] = pk;
            }
        }
        __syncthreads();

        // ---- B fragments: n = m16, k = quad*8 + j (contiguous 16 B) ----
        half8 Bf[4];
#pragma unroll
        for (int nt = 0; nt < 4; ++nt) {
            const int ch = nt * 16 + m16;
            Bf[nt] = *(const half8*)&Bbuf[ch][quad * 8];
        }

        // ---- A fragments (mask bits -> f16 0/1) + MFMA ----
#pragma unroll
        for (int mt = 0; mt < 4; ++mt) {
            const int p = wave * 64 + mt * 16 + m16;
            const unsigned int byte = mbuf[(step * 4 + quad) * 256 + p];
            half8 Af;
#pragma unroll
            for (int j = 0; j < 8; ++j)
                Af[j] = ((byte >> j) & 1u) ? (_Float16)1.0f : (_Float16)0.0f;
#pragma unroll
            for (int nt = 0; nt < 4; ++nt)
                acc[mt][nt] = __builtin_amdgcn_mfma_f32_16x16x32_f16(
                    Af, Bf[nt], acc[mt][nt], 0, 0, 0);
        }
        __syncthreads();
    }

    // ---- epilogue: C/D layout col=lane&15 (ch), row=quad*4+reg (p) ----
#pragma unroll
    for (int mt = 0; mt < 4; ++mt) {
#pragma unroll
        for (int nt = 0; nt < 4; ++nt) {
#pragma unroll
            for (int reg = 0; reg < 4; ++reg) {
                const int p = wave * 64 + mt * 16 + quad * 4 + reg;
                const int ch = ch0 + nt * 16 + m16;
                atomicAdd(&sums[p * R_FEAT + ch], acc[mt][nt][reg]);
            }
        }
    }
}

// ---------------- Kernel 3: heads + cls softmax + exp(obj) -----------------
__global__ __launch_bounds__(256) void head_kernel(
    const float* __restrict__ sums,      // (P,R)
    const float* __restrict__ pcnt,      // (MB_BLOCKS, P)
    const float* __restrict__ Wc,        // (R,21)
    const float* __restrict__ bc,        // (21)
    const float* __restrict__ Wo,        // (R,21)
    const float* __restrict__ bo,        // (21)
    float* __restrict__ cls_p,           // (P,21)
    float* __restrict__ eobj,            // (P,21)
    float* __restrict__ colsum)          // (21)
{
    const int p = blockIdx.x;
    const int t = threadIdx.x;

    __shared__ float roi[R_FEAT];
    __shared__ float red[256];
    __shared__ float part[4][64];
    __shared__ float lg[48];
    __shared__ float cmax_s, csum_s;

    float csum = 0.0f;
    for (int b = t; b < MB_BLOCKS; b += 256) csum += pcnt[b * 256 + p];
    red[t] = csum;
    __syncthreads();
    for (int s = 128; s > 0; s >>= 1) {
        if (t < s) red[t] += red[t + s];
        __syncthreads();
    }
    const float cntv = fmaxf(red[0], 1.0f);

    roi[t] = sums[p * R_FEAT + t] / cntv;
    __syncthreads();

    const int c2 = t & 63;
    const int qk = t >> 6;
    float accv = 0.0f;
    if (c2 < 2 * NCLS) {
        const float* __restrict__ W = (c2 < NCLS) ? Wc : Wo;
        const int cc = (c2 < NCLS) ? c2 : c2 - NCLS;
        const int r0 = qk * 64;
#pragma unroll
        for (int r = 0; r < 64; ++r)
            accv = fmaf(roi[r0 + r], W[(r0 + r) * NCLS + cc], accv);
    }
    part[qk][c2] = accv;
    __syncthreads();

    if (t < 2 * NCLS) {
        const float v = part[0][t] + part[1][t] + part[2][t] + part[3][t];
        lg[t] = v + ((t < NCLS) ? bc[t] : bo[t - NCLS]);
    }
    __syncthreads();

    if (t == 0) {
        float m = lg[0];
        for (int c = 1; c < NCLS; ++c) m = fmaxf(m, lg[c]);
        float sacc = 0.0f;
        for (int c = 0; c < NCLS; ++c) sacc += expf(lg[c] - m);
        cmax_s = m; csum_s = sacc;
    }
    __syncthreads();

    if (t < NCLS) {
        cls_p[p * NCLS + t] = expf(lg[t] - cmax_s) / csum_s;
    } else if (t >= NCLS && t < 2 * NCLS) {
        const int c = t - NCLS;
        const float eo = expf(lg[t]);      // |logit| ~ 0.02: no max needed
        eobj[p * NCLS + c] = eo;
        atomicAdd(&colsum[c], eo);
    }
}

// ---------------- Kernel 4: final product ----------------------------------
__global__ __launch_bounds__(256) void final_kernel(
    const float* __restrict__ cls_p,   // (P,21)
    const float* __restrict__ eobj,    // (P,21)
    const float* __restrict__ colsum,  // (21)
    float* __restrict__ out)           // (P,21)
{
    const int t = threadIdx.x;
    for (int k = t; k < P_PROP * NCLS; k += 256) {
        const int p = k / NCLS;
        const int c = k - p * NCLS;
        out[k] = cls_p[k] * eobj[k] / colsum[c];
    }
}

// ---------------- launch ----------------------------------------------------
extern "C" void kernel_launch(void* const* d_in, const int* in_sizes, int n_in,
                              void* d_out, int out_size, void* d_ws, size_t ws_size,
                              hipStream_t stream) {
    const float* proposals = (const float*)d_in[0];  // (256,6)
    const float* xyz       = (const float*)d_in[1];  // (100000,3)
    const float* feats     = (const float*)d_in[2];  // (100000,256)
    const float* Wc        = (const float*)d_in[3];  // (256,21)
    const float* bc        = (const float*)d_in[4];  // (21)
    const float* Wo        = (const float*)d_in[5];  // (256,21)
    const float* bo        = (const float*)d_in[6];  // (21)
    float* out = (float*)d_out;                      // (256,21)

    char* ws = (char*)d_ws;
    float* sums   = (float*)(ws + WS_SUMS);
    float* colsum = (float*)(ws + WS_COLSUM);
    float* pcnt   = (float*)(ws + WS_PCNT);
    float* cls_p  = (float*)(ws + WS_CLSP);
    float* eobj   = (float*)(ws + WS_EOBJ);
    unsigned char* maskT = (unsigned char*)(ws + WS_MASK);

    mask_kernel<<<MB_BLOCKS, 256, 0, stream>>>(proposals, xyz, maskT, pcnt,
                                               (float*)(ws + WS_SUMS));
    gemm_kernel<<<NCHUNK * 4, 256, 0, stream>>>(feats, maskT, sums);
    head_kernel<<<P_PROP, 256, 0, stream>>>(sums, pcnt, Wc, bc, Wo, bo,
                                            cls_p, eobj, colsum);
    final_kernel<<<1, 256, 0, stream>>>(cls_p, eobj, colsum, out);
}

// Round 7
// 252.127 us; speedup vs baseline: 4.6223x; 1.0180x over previous
//
#include <hip/hip_runtime.h>
#include <math.h>

#define N_PTS 100000
#define P_PROP 256
#define R_FEAT 256
#define NCLS 21              // C + 1
#define KB_TOT 12800         // mask rows (102400 padded points / 8)
#define MB_BLOCKS 400        // mask kernel blocks; block b covers points [b*256, +256)
#define KC 800               // points per gemm k-chunk
#define KSTEPS 25            // KC / 32
#define NCHUNK 128           // NCHUNK * KC = 102400
#define NT 8                 // channel tiles of 32
#define KPAD 40              // LDS k stride in halves (80 B, 16B-aligned)

// ws layout (bytes):
#define WS_SUMS    0         // 256*256*4 = 262144 (zeroed by mask kernel)
#define WS_COLSUM  262144    // 21*4, zero region padded to 262400
#define WS_PCNT    262400    // 400*256*4 = 409600
#define WS_CLSP    672000    // 21504
#define WS_EOBJ    693504    // 21504
#define WS_MASK    715008    // 12800*256 = 3276800  (ends 3991808)

typedef _Float16 half8 __attribute__((ext_vector_type(8)));
typedef float f32x4 __attribute__((ext_vector_type(4)));

// ---------------- Kernel 1: transposed byte-mask + partial counts ----------
// (unchanged from R6 — verified correct)
__global__ __launch_bounds__(256) void mask_kernel(
    const float* __restrict__ proposals,   // (P,6)
    const float* __restrict__ xyz,         // (N,3)
    unsigned char* __restrict__ maskT,     // (KB_TOT, 256)
    float* __restrict__ pcnt,              // (MB_BLOCKS, 256)
    float* __restrict__ ws_zero)           // 65600 floats to zero
{
    const int b = blockIdx.x;
    const int t = threadIdx.x;
    const int wave = t >> 6;
    const int lane = t & 63;

    {
        float* z = ws_zero + b * 164;
        for (int j = t; j < 164; j += 256) z[j] = 0.0f;
    }

    __shared__ float lox[P_PROP], hix[P_PROP];
    __shared__ float loy[P_PROP], hiy[P_PROP];
    __shared__ float loz[P_PROP], hiz[P_PROP];
    __shared__ unsigned long long wd[P_PROP][4];   // [p][wave]

    {
        const float cx = proposals[t * 6 + 0];
        const float cy = proposals[t * 6 + 1];
        const float cz = proposals[t * 6 + 2];
        const float hx = proposals[t * 6 + 3] * 0.5f;
        const float hy = proposals[t * 6 + 4] * 0.5f;
        const float hz = proposals[t * 6 + 5] * 0.5f;
        lox[t] = cx - hx; hix[t] = cx + hx;
        loy[t] = cy - hy; hiy[t] = cy + hy;
        loz[t] = cz - hz; hiz[t] = cz + hz;
    }
    __syncthreads();

    const int i = b * 256 + wave * 64 + lane;
    float px = 3.0e9f, py = 3.0e9f, pz = 3.0e9f;
    if (i < N_PTS) {
        px = xyz[3 * i + 0];
        py = xyz[3 * i + 1];
        pz = xyz[3 * i + 2];
    }

    for (int p = 0; p < P_PROP; ++p) {
        const bool in = (px >= lox[p]) & (px <= hix[p]) &
                        (py >= loy[p]) & (py <= hiy[p]) &
                        (pz >= loz[p]) & (pz <= hiz[p]);
        const unsigned long long w = __ballot(in);
        if (lane == 0) wd[p][wave] = w;
    }
    __syncthreads();

    {
        const unsigned long long* q = wd[t];
        const int c = __popcll(q[0]) + __popcll(q[1]) +
                      __popcll(q[2]) + __popcll(q[3]);
        pcnt[b * 256 + t] = (float)c;
    }

    const int r = t >> 3;        // local kb 0..31
    const int seg = t & 7;
    const unsigned char* wb = (const unsigned char*)wd;
    unsigned int outw[8];
#pragma unroll
    for (int d = 0; d < 8; ++d) {
        unsigned int v = 0;
#pragma unroll
        for (int u = 0; u < 4; ++u) {
            const int p = seg * 32 + d * 4 + u;
            v |= ((unsigned int)wb[p * 32 + r]) << (8 * u);
        }
        outw[d] = v;
    }
    unsigned int* dst = (unsigned int*)(maskT + ((size_t)(b * 32 + r)) * 256 + seg * 32);
#pragma unroll
    for (int d = 0; d < 8; ++d) dst[d] = outw[d];
}

// ---------------- Kernel 2: pipelined masked-sum GEMM (f16 MFMA) -----------
// grid = 1024 = 128 k-chunks x 8 ch-tiles(32). 256 threads = 4 waves.
// Per 32-point step: B prefetched as one float4/thread (coalesced), packed
// f16 [ch][k] into double-buffered LDS via shfl pairing; A = mask bytes
// prefetched into registers (no LDS); 8 MFMA/wave/step; ONE barrier/step.
// Epilogue: fp32 atomicAdd of the 256x32 C tile.
__global__ __launch_bounds__(256, 4) void gemm_kernel(
    const float* __restrict__ feats,               // (N,R)
    const unsigned char* __restrict__ maskT,       // (KB_TOT, 256)
    float* __restrict__ sums)                      // (P,R)
{
    const int bid = blockIdx.x;
    const int ch0 = (bid & 7) * 32;
    const int chunk = bid >> 3;
    const int t = threadIdx.x;
    const int wave = t >> 6;
    const int lane = t & 63;
    const int quad = lane >> 4;
    const int m16 = lane & 15;

    const int sr = t >> 3;        // staging row 0..31
    const int sc = (t & 7) * 4;   // staging ch offset (float4)

    __shared__ __align__(16) _Float16 Bbuf[2][32][KPAD];   // 5120 B

    f32x4 acc[4][2];
#pragma unroll
    for (int mt = 0; mt < 4; ++mt) {
        acc[mt][0] = (f32x4)0.0f;
        acc[mt][1] = (f32x4)0.0f;
    }

    const int kbase = chunk * KC;
    const unsigned char* mbase = maskT + (size_t)(chunk * (KC / 8)) * 256;
    const int pbase = wave * 64 + m16;

    // ---- prefetch step 0 ----
    float4 fstage;
    {
        const int rg = min(kbase + sr, N_PTS - 1);
        fstage = *(const float4*)(feats + (size_t)rg * R_FEAT + ch0 + sc);
    }
    unsigned int mstage[4];
#pragma unroll
    for (int mt = 0; mt < 4; ++mt)
        mstage[mt] = mbase[(size_t)quad * 256 + pbase + mt * 16];

    for (int step = 0; step < KSTEPS; ++step) {
        _Float16* Bb = &Bbuf[step & 1][0][0];

        // ---- pack current stage into LDS (even-sr threads write pairs) ----
        {
            const _Float16 h0 = (_Float16)fstage.x, h1 = (_Float16)fstage.y;
            const _Float16 h2 = (_Float16)fstage.z, h3 = (_Float16)fstage.w;
            const unsigned int m0 =
                ((unsigned int)__builtin_bit_cast(unsigned short, h1) << 16) |
                (unsigned int)__builtin_bit_cast(unsigned short, h0);
            const unsigned int m1 =
                ((unsigned int)__builtin_bit_cast(unsigned short, h3) << 16) |
                (unsigned int)__builtin_bit_cast(unsigned short, h2);
            const unsigned int p0 = __shfl(m0, lane ^ 8, 64);
            const unsigned int p1 = __shfl(m1, lane ^ 8, 64);
            if ((sr & 1) == 0) {
                const unsigned int o0 = (p0 << 16) | (m0 & 0xFFFFu);
                const unsigned int o1 = (p0 & 0xFFFF0000u) | (m0 >> 16);
                const unsigned int o2 = (p1 << 16) | (m1 & 0xFFFFu);
                const unsigned int o3 = (p1 & 0xFFFF0000u) | (m1 >> 16);
                *(unsigned int*)&Bb[(sc + 0) * KPAD + sr] = o0;
                *(unsigned int*)&Bb[(sc + 1) * KPAD + sr] = o1;
                *(unsigned int*)&Bb[(sc + 2) * KPAD + sr] = o2;
                *(unsigned int*)&Bb[(sc + 3) * KPAD + sr] = o3;
            }
        }
        unsigned int mcur[4];
#pragma unroll
        for (int mt = 0; mt < 4; ++mt) mcur[mt] = mstage[mt];

        __syncthreads();   // one barrier per step (dbuf makes W(i+1) safe)

        // ---- prefetch step+1 (after barrier so its drain can't stall us) --
        if (step + 1 < KSTEPS) {
            const int rg = min(kbase + (step + 1) * 32 + sr, N_PTS - 1);
            fstage = *(const float4*)(feats + (size_t)rg * R_FEAT + ch0 + sc);
#pragma unroll
            for (int mt = 0; mt < 4; ++mt)
                mstage[mt] = mbase[(size_t)((step + 1) * 4 + quad) * 256 + pbase + mt * 16];
        }

        // ---- B fragments: n=m16, k=quad*8+j (16B aligned, ~2-way max) ----
        half8 Bf[2];
        Bf[0] = *(const half8*)&Bbuf[step & 1][m16][quad * 8];
        Bf[1] = *(const half8*)&Bbuf[step & 1][16 + m16][quad * 8];

        // ---- A expand (mask bits -> f16 0/1, registers only) + MFMA ------
#pragma unroll
        for (int mt = 0; mt < 4; ++mt) {
            const unsigned int b = mcur[mt];
            half8 Af;
#pragma unroll
            for (int j = 0; j < 8; ++j)
                Af[j] = ((b >> j) & 1u) ? (_Float16)1.0f : (_Float16)0.0f;
            acc[mt][0] = __builtin_amdgcn_mfma_f32_16x16x32_f16(Af, Bf[0], acc[mt][0], 0, 0, 0);
            acc[mt][1] = __builtin_amdgcn_mfma_f32_16x16x32_f16(Af, Bf[1], acc[mt][1], 0, 0, 0);
        }
    }

    // ---- epilogue: C/D layout col(ch)=m16, row(p)=quad*4+reg -------------
#pragma unroll
    for (int mt = 0; mt < 4; ++mt) {
#pragma unroll
        for (int nt = 0; nt < 2; ++nt) {
#pragma unroll
            for (int reg = 0; reg < 4; ++reg) {
                const int p = wave * 64 + mt * 16 + quad * 4 + reg;
                const int ch = ch0 + nt * 16 + m16;
                atomicAdd(&sums[p * R_FEAT + ch], acc[mt][nt][reg]);
            }
        }
    }
}

// ---------------- Kernel 3: heads + cls softmax + exp(obj) -----------------
__global__ __launch_bounds__(256) void head_kernel(
    const float* __restrict__ sums,      // (P,R)
    const float* __restrict__ pcnt,      // (MB_BLOCKS, P)
    const float* __restrict__ Wc,        // (R,21)
    const float* __restrict__ bc,        // (21)
    const float* __restrict__ Wo,        // (R,21)
    const float* __restrict__ bo,        // (21)
    float* __restrict__ cls_p,           // (P,21)
    float* __restrict__ eobj,            // (P,21)
    float* __restrict__ colsum)          // (21)
{
    const int p = blockIdx.x;
    const int t = threadIdx.x;

    __shared__ float roi[R_FEAT];
    __shared__ float red[256];
    __shared__ float part[4][64];
    __shared__ float lg[48];
    __shared__ float cmax_s, csum_s;

    float csum = 0.0f;
    for (int b = t; b < MB_BLOCKS; b += 256) csum += pcnt[b * 256 + p];
    red[t] = csum;
    __syncthreads();
    for (int s = 128; s > 0; s >>= 1) {
        if (t < s) red[t] += red[t + s];
        __syncthreads();
    }
    const float cntv = fmaxf(red[0], 1.0f);

    roi[t] = sums[p * R_FEAT + t] / cntv;
    __syncthreads();

    const int c2 = t & 63;
    const int qk = t >> 6;
    float accv = 0.0f;
    if (c2 < 2 * NCLS) {
        const float* __restrict__ W = (c2 < NCLS) ? Wc : Wo;
        const int cc = (c2 < NCLS) ? c2 : c2 - NCLS;
        const int r0 = qk * 64;
#pragma unroll
        for (int r = 0; r < 64; ++r)
            accv = fmaf(roi[r0 + r], W[(r0 + r) * NCLS + cc], accv);
    }
    part[qk][c2] = accv;
    __syncthreads();

    if (t < 2 * NCLS) {
        const float v = part[0][t] + part[1][t] + part[2][t] + part[3][t];
        lg[t] = v + ((t < NCLS) ? bc[t] : bo[t - NCLS]);
    }
    __syncthreads();

    if (t == 0) {
        float m = lg[0];
        for (int c = 1; c < NCLS; ++c) m = fmaxf(m, lg[c]);
        float sacc = 0.0f;
        for (int c = 0; c < NCLS; ++c) sacc += expf(lg[c] - m);
        cmax_s = m; csum_s = sacc;
    }
    __syncthreads();

    if (t < NCLS) {
        cls_p[p * NCLS + t] = expf(lg[t] - cmax_s) / csum_s;
    } else if (t >= NCLS && t < 2 * NCLS) {
        const int c = t - NCLS;
        const float eo = expf(lg[t]);      // |logit| ~ 0.02: no max needed
        eobj[p * NCLS + c] = eo;
        atomicAdd(&colsum[c], eo);
    }
}

// ---------------- Kernel 4: final product ----------------------------------
__global__ __launch_bounds__(256) void final_kernel(
    const float* __restrict__ cls_p,   // (P,21)
    const float* __restrict__ eobj,    // (P,21)
    const float* __restrict__ colsum,  // (21)
    float* __restrict__ out)           // (P,21)
{
    const int t = threadIdx.x;
    for (int k = t; k < P_PROP * NCLS; k += 256) {
        const int p = k / NCLS;
        const int c = k - p * NCLS;
        out[k] = cls_p[k] * eobj[k] / colsum[c];
    }
}

// ---------------- launch ----------------------------------------------------
extern "C" void kernel_launch(void* const* d_in, const int* in_sizes, int n_in,
                              void* d_out, int out_size, void* d_ws, size_t ws_size,
                              hipStream_t stream) {
    const float* proposals = (const float*)d_in[0];  // (256,6)
    const float* xyz       = (const float*)d_in[1];  // (100000,3)
    const float* feats     = (const float*)d_in[2];  // (100000,256)
    const float* Wc        = (const float*)d_in[3];  // (256,21)
    const float* bc        = (const float*)d_in[4];  // (21)
    const float* Wo        = (const float*)d_in[5];  // (256,21)
    const float* bo        = (const float*)d_in[6];  // (21)
    float* out = (float*)d_out;                      // (256,21)

    char* ws = (char*)d_ws;
    float* sums   = (float*)(ws + WS_SUMS);
    float* colsum = (float*)(ws + WS_COLSUM);
    float* pcnt   = (float*)(ws + WS_PCNT);
    float* cls_p  = (float*)(ws + WS_CLSP);
    float* eobj   = (float*)(ws + WS_EOBJ);
    unsigned char* maskT = (unsigned char*)(ws + WS_MASK);

    mask_kernel<<<MB_BLOCKS, 256, 0, stream>>>(proposals, xyz, maskT, pcnt,
                                               (float*)(ws + WS_SUMS));
    gemm_kernel<<<NCHUNK * NT, 256, 0, stream>>>(feats, maskT, sums);
    head_kernel<<<P_PROP, 256, 0, stream>>>(sums, pcnt, Wc, bc, Wo, bo,
                                            cls_p, eobj, colsum);
    final_kernel<<<1, 256, 0, stream>>>(cls_p, eobj, colsum, out);
}